// Round 2
// baseline (180.071 us; speedup 1.0000x reference)
//
#include <hip/hip_runtime.h>
#include <math.h>

// R6 (resubmit; previous run died to container infra failure, not kernel).
// DAG restructure. bnapply_pad deleted (BN1+pad fused into mid3x3 via
// chunked LDS staging). adder_ds moved off the critical path: it now rides
// in the mid launch (blocks [512,1024)) since its output A / bnds stats /
// KL-t0 are only consumed in final_kernel. 5 kernels:
//   minmax(64) -> front'(336: c1+PEG, f_c2 writer, KL t3)
//   -> mid(1024: fused bn1+3x3 [0,512) + adder_ds [512,1024))
//   -> back(1024) -> final(784)

#define HW 784      // 28*28
#define NB 4
#define STAGE 100

// ---------------- wave/block reduction helpers (wave64) --------------------
__device__ __forceinline__ float wredSum(float v){
  for (int o = 32; o > 0; o >>= 1) v += __shfl_down(v, o, 64);
  return v;
}
__device__ __forceinline__ float wredMax(float v){
  for (int o = 32; o > 0; o >>= 1) v = fmaxf(v, __shfl_down(v, o, 64));
  return v;
}
__device__ __forceinline__ float wredMin(float v){
  for (int o = 32; o > 0; o >>= 1) v = fminf(v, __shfl_down(v, o, 64));
  return v;
}
__device__ __forceinline__ double wredSumD(double v){
  for (int o = 32; o > 0; o >>= 1) v += __shfl_down(v, o, 64);
  return v;
}

// blockDim = 256 (4 waves)
__device__ float blockMin4(float v){
  __shared__ float shn[4];
  __syncthreads();
  v = wredMin(v);
  if ((threadIdx.x & 63) == 0) shn[threadIdx.x >> 6] = v;
  __syncthreads();
  return fminf(fminf(shn[0], shn[1]), fminf(shn[2], shn[3]));
}
__device__ float blockMax4(float v){
  __shared__ float shx[4];
  __syncthreads();
  v = wredMax(v);
  if ((threadIdx.x & 63) == 0) shx[threadIdx.x >> 6] = v;
  __syncthreads();
  return fmaxf(fmaxf(shx[0], shx[1]), fmaxf(shx[2], shx[3]));
}

// ---- per-block BN stats: 4 channels, sum+sumsq, double atomics (256 thr) --
__device__ void stats4(float v0, float v1, float v2, float v3,
                       double* sumP, double* sqP, int oc0){
  __shared__ double sred[4][8];
  __syncthreads();
  const int w = threadIdx.x >> 6;
  float vv[4] = {v0, v1, v2, v3};
  #pragma unroll
  for (int i = 0; i < 4; i++){
    double d = (double)vv[i];
    double s = wredSumD(d);
    double q = wredSumD(d * d);
    if ((threadIdx.x & 63) == 0){ sred[w][i] = s; sred[w][4 + i] = q; }
  }
  __syncthreads();
  if (threadIdx.x < 8){
    double tot = sred[0][threadIdx.x] + sred[1][threadIdx.x]
               + sred[2][threadIdx.x] + sred[3][threadIdx.x];
    int i = threadIdx.x & 3;
    if (threadIdx.x < 4) atomicAdd(&sumP[oc0 + i], tot);
    else                 atomicAdd(&sqP[oc0 + i],  tot);
  }
}
__device__ void stats2(float v0, float v1, double* sumP, double* sqP, int oc0){
  __shared__ double sred2[4][4];
  __syncthreads();
  const int w = threadIdx.x >> 6;
  float vv[2] = {v0, v1};
  #pragma unroll
  for (int i = 0; i < 2; i++){
    double d = (double)vv[i];
    double s = wredSumD(d);
    double q = wredSumD(d * d);
    if ((threadIdx.x & 63) == 0){ sred2[w][i] = s; sred2[w][2 + i] = q; }
  }
  __syncthreads();
  if (threadIdx.x < 4){
    double tot = sred2[0][threadIdx.x] + sred2[1][threadIdx.x]
               + sred2[2][threadIdx.x] + sred2[3][threadIdx.x];
    int i = threadIdx.x & 1;
    if (threadIdx.x < 2) atomicAdd(&sumP[oc0 + i], tot);
    else                 atomicAdd(&sqP[oc0 + i],  tot);
  }
}

// ---- KL partial accumulation: 4 sums -> 4 double atomics (256 thr) --------
__device__ void klAccum(float se, float sel, float sef, float sq, double* dst){
  __shared__ double kls[4][4];
  __syncthreads();
  const int w = threadIdx.x >> 6;
  double a0 = wredSumD((double)se);
  double a1 = wredSumD((double)sel);
  double a2 = wredSumD((double)sef);
  double a3 = wredSumD((double)sq);
  if ((threadIdx.x & 63) == 0){
    kls[w][0] = a0; kls[w][1] = a1; kls[w][2] = a2; kls[w][3] = a3;
  }
  __syncthreads();
  if (threadIdx.x < 4){
    double tot = kls[0][threadIdx.x] + kls[1][threadIdx.x]
               + kls[2][threadIdx.x] + kls[3][threadIdx.x];
    atomicAdd(&dst[threadIdx.x], tot);
  }
}

// ---- bin reconstruction (reference op order; exact bin indices) -----------
__device__ __forceinline__ float reconv(float vv, float mn, float rng,
                                        const float* saff){
  float q = (vv - mn) / rng * 100.0f;
  int idx = (int)floorf(q);
  float nv = 0.0f;
  if (idx < STAGE){
    int ci = idx < 0 ? 0 : (idx > STAGE - 1 ? STAGE - 1 : idx);
    nv = vv * saff[ci];
  }
  return nv;
}

// ---- reduce 16 per-block minmax partials (race-free, no atomics) ----------
__device__ __forceinline__ void mmReduce(const float* mmbuf, int tens,
                                         float& mn, float& mx){
  mn = 3.402823466e38f; mx = -3.402823466e38f;
  #pragma unroll
  for (int k = 0; k < 16; k++){
    mn = fminf(mn, mmbuf[tens * 32 + k]);
    mx = fmaxf(mx, mmbuf[tens * 32 + 16 + k]);
  }
}

// --------------- K0: partial min/max of 4 weight tensors + zero stats ------
// grid = 64: tensor = blk>>4, slot = blk&15. Also zeroes dstat (1344 dbl).
// dstat layout: [0:256) ds_sum [256:512) ds_sq [512:576) bn1_s [576:640) bn1_q
//   [640:704) bn2_s [704:768) bn2_q [768:1024) bn3_s [1024:1280) bn3_q
//   [1280:1296) kl: tensor*4 + {se, sel, sef, sq}
__global__ __launch_bounds__(256) void minmax_kernel(
    const float* w0, int n0, const float* w1, int n1,
    const float* w2, int n2, const float* w3, int n3,
    float* mmbuf, double* dstat)
{
  if (threadIdx.x < 21) dstat[blockIdx.x * 21 + threadIdx.x] = 0.0;
  const int tens = blockIdx.x >> 4, slot = blockIdx.x & 15;
  const float* w; int n;
  if      (tens == 0){ w = w0; n = n0; }
  else if (tens == 1){ w = w1; n = n1; }
  else if (tens == 2){ w = w2; n = n2; }
  else               { w = w3; n = n3; }
  float mn = 3.402823466e38f, mx = -3.402823466e38f;
  for (int i = slot * 256 + threadIdx.x; i < n; i += 4096){
    float v = w[i];
    mn = fminf(mn, v); mx = fmaxf(mx, v);
  }
  mn = blockMin4(mn); mx = blockMax4(mx);
  if (threadIdx.x == 0){
    mmbuf[tens * 32 + slot]      = mn;
    mmbuf[tens * 32 + 16 + slot] = mx;
  }
}

// --------------- K1: front' — (adder_c1+PEG) + f_c2 writer + KL t3 ---------
// blocks [0,256): adder_c1+peg, 4 oc, 7-row tile (inline recon)
// blocks [256,320): recon+write f_c2 row (576 elems) + KL partial (t2)
// blocks [320,336): recon f_c3 slice (1024) + KL partial (t3)
__global__ __launch_bounds__(256) void front_kernel(
    const float* __restrict__ x,
    const float* __restrict__ w_c1, const float* __restrict__ aff_c1,
    const float* __restrict__ lap_c1,
    const float* __restrict__ w_c2, const float* __restrict__ aff_c2,
    const float* __restrict__ lap_c2, float* __restrict__ f_c2,
    const float* __restrict__ w_c3, const float* __restrict__ aff_c3,
    const float* __restrict__ lap_c3,
    const float* __restrict__ peg_w, const float* __restrict__ mmbuf,
    float* __restrict__ T2, double* __restrict__ dS)
{
  const int t = threadIdx.x;
  if (blockIdx.x < 256){
    // ---------------- adder_c1 + PEG ----------------
    const int a = blockIdx.x;
    const int rc = a & 3, og = (a >> 2) & 15, b = a >> 6;
    const int oc0 = og * 4;
    __shared__ float saffc[STAGE];
    __shared__ float swc[512];
    __shared__ float swp[36];
    __shared__ float sT1[4][256];
    if (t < STAGE) saffc[t] = aff_c1[t];
    if (t >= 128 && t < 164) swp[t - 128] = peg_w[oc0 * 9 + (t - 128)];
    float mn, mx; mmReduce(mmbuf, 1, mn, mx);
    const float rng = mx - mn;
    __syncthreads();
    for (int k = t; k < 512; k += 256)
      swc[k] = reconv(w_c1[oc0 * 128 + k], mn, rng, saffc);
    __syncthreads();

    if (t < 252){
      const int rr = t / 28;
      const int col = t - rr * 28;
      const int wr = rc * 7 - 1 + rr;
      float tv0 = 0, tv1 = 0, tv2 = 0, tv3 = 0;
      if (wr >= 0 && wr < 28){
        const float* xp = x + (size_t)b * 128 * HW + wr * 28 + col;
        float c0 = 0, c1 = 0, c2 = 0, c3 = 0;
        #pragma unroll 4
        for (int c = 0; c < 128; c++){
          float xv = xp[(size_t)c * HW];
          c0 += fabsf(xv - swc[c]);
          c1 += fabsf(xv - swc[128 + c]);
          c2 += fabsf(xv - swc[256 + c]);
          c3 += fabsf(xv - swc[384 + c]);
        }
        tv0 = -c0; tv1 = -c1; tv2 = -c2; tv3 = -c3;
      }
      sT1[0][t] = tv0; sT1[1][t] = tv1; sT1[2][t] = tv2; sT1[3][t] = tv3;
    }
    __syncthreads();
    float v0 = 0, v1 = 0, v2 = 0, v3 = 0;
    if (t < 196){
      const int r = t / 28, col = t - r * 28;
      float c0 = 0, c1 = 0, c2 = 0, c3 = 0;
      #pragma unroll
      for (int ky = 0; ky < 3; ky++){
        #pragma unroll
        for (int kx = 0; kx < 3; kx++){
          int cc = col + kx - 1;
          bool ok = (cc >= 0) && (cc < 28);
          int idx = ok ? ((r + ky) * 28 + cc) : 0;
          float p0 = ok ? sT1[0][idx] : 0.0f;
          float p1 = ok ? sT1[1][idx] : 0.0f;
          float p2 = ok ? sT1[2][idx] : 0.0f;
          float p3 = ok ? sT1[3][idx] : 0.0f;
          int wk = ky * 3 + kx;
          c0 += fabsf(p0 - swp[wk]);
          c1 += fabsf(p1 - swp[9 + wk]);
          c2 += fabsf(p2 - swp[18 + wk]);
          c3 += fabsf(p3 - swp[27 + wk]);
        }
      }
      v0 = -c0; v1 = -c1; v2 = -c2; v3 = -c3;
      const int opx = (rc * 7 + r) * 28 + col;
      float* op = T2 + ((size_t)(b * 64 + oc0)) * HW + opx;
      op[0] = v0; op[HW] = v1; op[2 * HW] = v2; op[3 * HW] = v3;
    }
    stats4(v0, v1, v2, v3, dS + 512, dS + 576, oc0);

    if (b == 0 && rc == 0){        // KL partial for tensor 1
      float se = 0, sel = 0, sef = 0, sq = 0;
      for (int k = t; k < 512; k += 256){
        float l = lap_c1[oc0 * 128 + k];
        float e = expf(l);
        se += e; sel += e * l; sef += e * swc[k];
        sq += expf(swc[k]);
      }
      klAccum(se, sel, sef, sq, dS + 1280 + 4);
    }
  } else if (blockIdx.x < 320){
    // ---------------- f_c2 writer + KL (tensor 2) ----------------
    const int j = blockIdx.x - 256;          // oc row 0..63, 576 elems
    __shared__ float saff2[STAGE];
    if (t < STAGE) saff2[t] = aff_c2[t];
    float mn, mx; mmReduce(mmbuf, 2, mn, mx);
    const float rng = mx - mn;
    __syncthreads();
    float se = 0, sel = 0, sef = 0, sq = 0;
    for (int k = t; k < 576; k += 256){
      float nv = reconv(w_c2[j * 576 + k], mn, rng, saff2);
      f_c2[j * 576 + k] = nv;
      float l = lap_c2[j * 576 + k];
      float e = expf(l);
      se += e; sel += e * l; sef += e * nv; sq += expf(nv);
    }
    klAccum(se, sel, sef, sq, dS + 1280 + 8);
  } else {
    // ---------------- KL (tensor 3) ----------------
    const int j = blockIdx.x - 320;          // slice of 1024
    __shared__ float saff3[STAGE];
    if (t < STAGE) saff3[t] = aff_c3[t];
    float mn, mx; mmReduce(mmbuf, 3, mn, mx);
    const float rng = mx - mn;
    __syncthreads();
    float se = 0, sel = 0, sef = 0, sq = 0;
    for (int k = t; k < 1024; k += 256){
      float nv = reconv(w_c3[j * 1024 + k], mn, rng, saff3);
      float l = lap_c3[j * 1024 + k];
      float e = expf(l);
      se += e; sel += e * l; sef += e * nv; sq += expf(nv);
    }
    klAccum(se, sel, sef, sq, dS + 1280 + 12);
  }
}

// --------------- K2: mid — fused bn1+pad+3x3 [0,512) + adder_ds [512,1024) -
// Branch A: 2 oc, 7-row px chunk. BN1 finalize inline (dS bn1 stats are
// complete at this kernel boundary), relu+zero-pad staged into LDS in 4
// channel-chunks of 16 ([16][9][32] = 18.4 KB), 3x3 L1-adder from LDS.
// Branch B: adder_ds verbatim from old front (8 oc, 196-px chunk, inline
// recon of its weight slice) + KL t0 riders. Output A only read in final.
__global__ __launch_bounds__(256) void mid_kernel(
    const float* __restrict__ x,
    const float* __restrict__ T2, const float* __restrict__ f_c2,
    const float* __restrict__ g1, const float* __restrict__ b1,
    const float* __restrict__ w_ds, const float* __restrict__ aff_ds,
    const float* __restrict__ lap_ds, const float* __restrict__ mmbuf,
    float* __restrict__ T3, float* __restrict__ A, double* __restrict__ dS)
{
  const int t = threadIdx.x;
  if (blockIdx.x < 512){
    // ---------------- fused bn1 + pad + adder 3x3 ----------------
    const int a = blockIdx.x;
    const int chunk = a & 3, og = (a >> 2) & 31, b = a >> 7;
    const int oc0 = og * 2;
    __shared__ float ssc[64], ssb[64];
    __shared__ float sT[16 * 288];           // [c_local][rr 0..8][cl 0..31]
    if (t < 64){
      double s  = dS[512 + t] * (1.0 / 3136.0);
      double vr = dS[576 + t] * (1.0 / 3136.0) - s * s;
      float scale = g1[t] * rsqrtf((float)vr + 1e-5f);
      ssc[t] = scale; ssb[t] = b1[t] - (float)s * scale;
    }
    const float* __restrict__ wA = f_c2 + oc0 * 576;
    const float* __restrict__ wB = wA + 576;
    const int r = t / 28;                    // output row within 7-row tile
    const int col = t - r * 28;
    const int row0 = chunk * 7;              // output rows row0..row0+6
    float c0acc = 0.0f, c1acc = 0.0f;

    for (int cc = 0; cc < 4; cc++){
      const int cbase = cc * 16;
      __syncthreads();                       // ssc ready / prev compute done
      #pragma unroll
      for (int k = 0; k < 18; k++){          // 18*256 = 4608 = 16*9*32
        int i = t + k * 256;
        int cl = i & 31;
        int rem = i >> 5;                    // c_local*9 + rr
        int c_local = rem / 9;
        int rr = rem - c_local * 9;
        int wr = row0 - 1 + rr;
        int wc = cl - 1;
        float v = 0.0f;
        if (wr >= 0 && wr < 28 && wc >= 0 && wc < 28){
          int c = cbase + c_local;
          float raw = T2[((size_t)(b * 64 + c)) * HW + wr * 28 + wc];
          v = fmaxf(raw * ssc[c] + ssb[c], 0.0f);
        }
        sT[i] = v;
      }
      __syncthreads();
      if (t < 196){
        #pragma unroll 2
        for (int c = 0; c < 16; c++){
          const float* p = sT + c * 288 + r * 32 + col;
          float t0 = p[0],  t1 = p[1],  t2 = p[2];
          float t3 = p[32], t4 = p[33], t5 = p[34];
          float t6 = p[64], t7 = p[65], t8 = p[66];
          const float* wa = wA + (cbase + c) * 9;
          const float* wb = wB + (cbase + c) * 9;
          c0acc += fabsf(t0 - wa[0]) + fabsf(t1 - wa[1]) + fabsf(t2 - wa[2])
                 + fabsf(t3 - wa[3]) + fabsf(t4 - wa[4]) + fabsf(t5 - wa[5])
                 + fabsf(t6 - wa[6]) + fabsf(t7 - wa[7]) + fabsf(t8 - wa[8]);
          c1acc += fabsf(t0 - wb[0]) + fabsf(t1 - wb[1]) + fabsf(t2 - wb[2])
                 + fabsf(t3 - wb[3]) + fabsf(t4 - wb[4]) + fabsf(t5 - wb[5])
                 + fabsf(t6 - wb[6]) + fabsf(t7 - wb[7]) + fabsf(t8 - wb[8]);
        }
      }
    }
    float v0 = 0.0f, v1 = 0.0f;
    if (t < 196){
      v0 = -c0acc; v1 = -c1acc;
      const int px = chunk * 196 + t;        // = (row0+r)*28 + col
      T3[((size_t)(b * 64 + oc0)) * HW + px]     = v0;
      T3[((size_t)(b * 64 + oc0 + 1)) * HW + px] = v1;
    }
    stats2(v0, v1, dS + 640, dS + 704, oc0);
  } else {
    // ---------------- adder_ds (rider) ----------------
    const int a = blockIdx.x - 512;
    const int chunk = a & 3, og = (a >> 2) & 31, b = a >> 7;
    const int oc0 = og * 8;
    __shared__ float saff[STAGE];
    __shared__ float sw[1024];
    if (t < STAGE) saff[t] = aff_ds[t];
    float mn, mx; mmReduce(mmbuf, 0, mn, mx);
    const float rng = mx - mn;
    __syncthreads();
    for (int k = t; k < 1024; k += 256)
      sw[k] = reconv(w_ds[oc0 * 128 + k], mn, rng, saff);
    __syncthreads();

    const int px = chunk * 196 + t;
    float v0=0,v1=0,v2=0,v3=0,v4=0,v5=0,v6=0,v7=0;
    if (t < 196){
      const float* xp = x + (size_t)b * 128 * HW + px;
      float c0=0,c1=0,c2=0,c3=0,c4=0,c5=0,c6=0,c7=0;
      #pragma unroll 4
      for (int c = 0; c < 128; c++){
        float xv = xp[(size_t)c * HW];
        c0 += fabsf(xv - sw[c]);
        c1 += fabsf(xv - sw[128 + c]);
        c2 += fabsf(xv - sw[256 + c]);
        c3 += fabsf(xv - sw[384 + c]);
        c4 += fabsf(xv - sw[512 + c]);
        c5 += fabsf(xv - sw[640 + c]);
        c6 += fabsf(xv - sw[768 + c]);
        c7 += fabsf(xv - sw[896 + c]);
      }
      v0=-c0; v1=-c1; v2=-c2; v3=-c3; v4=-c4; v5=-c5; v6=-c6; v7=-c7;
      float* op = A + ((size_t)(b * 256 + oc0)) * HW + px;
      op[0]=v0; op[HW]=v1; op[2*HW]=v2; op[3*HW]=v3;
      op[4*HW]=v4; op[5*HW]=v5; op[6*HW]=v6; op[7*HW]=v7;
    }
    stats4(v0, v1, v2, v3, dS + 0, dS + 256, oc0);
    stats4(v4, v5, v6, v7, dS + 0, dS + 256, oc0 + 4);

    if (b == 0 && chunk == 0){     // KL partial for tensor 0 (own slice)
      float se = 0, sel = 0, sef = 0, sq = 0;
      for (int k = t; k < 1024; k += 256){
        float l = lap_ds[oc0 * 128 + k];
        float e = expf(l);
        se += e; sel += e * l; sef += e * sw[k];
        sq += expf(sw[k]);
      }
      klAccum(se, sel, sef, sq, dS + 1280 + 0);
    }
  }
}

// --------------- K3: adder 1x1 64->256 (bn2 inline, inline recon) ----------
__global__ __launch_bounds__(256) void back_kernel(
    const float* __restrict__ T3, const float* __restrict__ w_c3,
    const float* __restrict__ aff_c3, const float* __restrict__ mmbuf,
    const float* __restrict__ g2, const float* __restrict__ b2,
    float* __restrict__ out, double* __restrict__ dS)
{
  const int t = threadIdx.x;
  const int a = blockIdx.x;
  const int chunk = a & 3, og = (a >> 2) & 63, b = a >> 8;
  const int oc0 = og * 4;
  __shared__ float ssc[64], ssb[64], sw[256], saff[STAGE];
  if (t < 64){
    double s  = dS[640 + t] * (1.0 / 3136.0);
    double vr = dS[704 + t] * (1.0 / 3136.0) - s * s;
    float scale = g2[t] * rsqrtf((float)vr + 1e-5f);
    ssc[t] = scale; ssb[t] = b2[t] - (float)s * scale;
  }
  if (t >= 128 && t < 128 + STAGE) saff[t - 128] = aff_c3[t - 128];
  float mn, mx; mmReduce(mmbuf, 3, mn, mx);
  const float rng = mx - mn;
  __syncthreads();
  sw[t] = reconv(w_c3[oc0 * 64 + t], mn, rng, saff);
  __syncthreads();

  const int px = chunk * 196 + t;
  float v0 = 0, v1 = 0, v2 = 0, v3 = 0;
  if (t < 196){
    const float* bp = T3 + (size_t)b * 64 * HW + px;
    float c0 = 0, c1 = 0, c2 = 0, c3 = 0;
    #pragma unroll 4
    for (int c = 0; c < 64; c++){
      float raw = bp[(size_t)c * HW];
      float vv = fmaxf(raw * ssc[c] + ssb[c], 0.0f);
      c0 += fabsf(vv - sw[c]);
      c1 += fabsf(vv - sw[64 + c]);
      c2 += fabsf(vv - sw[128 + c]);
      c3 += fabsf(vv - sw[192 + c]);
    }
    v0 = -c0; v1 = -c1; v2 = -c2; v3 = -c3;
    float* op = out + ((size_t)(b * 256 + oc0)) * HW + px;
    op[0] = v0; op[HW] = v1; op[2 * HW] = v2; op[3 * HW] = v3;
  }
  stats4(v0, v1, v2, v3, dS + 768, dS + 1024, oc0);
}

// --------------- K4: bn3 + bnds finalize, residual, relu, kl ---------------
__global__ __launch_bounds__(256) void final_kernel(
    float* __restrict__ out, const float* __restrict__ A,
    const float* __restrict__ g3, const float* __restrict__ b3,
    const float* __restrict__ gds, const float* __restrict__ bds,
    const double* __restrict__ dS)
{
  __shared__ float s3c[256], s3b[256], sdc[256], sdb[256];
  const int t = threadIdx.x;
  {
    double s  = dS[768 + t] * (1.0 / 3136.0);
    double vr = dS[1024 + t] * (1.0 / 3136.0) - s * s;
    float scale = g3[t] * rsqrtf((float)vr + 1e-5f);
    s3c[t] = scale; s3b[t] = b3[t] - (float)s * scale;
    s  = dS[t] * (1.0 / 3136.0);
    vr = dS[256 + t] * (1.0 / 3136.0) - s * s;
    scale = gds[t] * rsqrtf((float)vr + 1e-5f);
    sdc[t] = scale; sdb[t] = bds[t] - (float)s * scale;
  }
  __syncthreads();
  #pragma unroll
  for (int k = 0; k < 4; k++){
    int n = blockIdx.x * 1024 + k * 256 + t;
    int c = (n / HW) & 255;
    float h = out[n], aa = A[n];
    float r = fmaxf(aa * sdc[c] + sdb[c], 0.0f);
    out[n] = fmaxf(h * s3c[c] + s3b[c] + r, 0.0f);
  }
  if (blockIdx.x == 0 && t == 0){
    const int ns[4] = {32768, 8192, 36864, 16384};
    float kl = 0.0f;
    #pragma unroll
    for (int q = 0; q < 4; q++){
      double se  = dS[1280 + q * 4];
      double sel = dS[1280 + q * 4 + 1];
      double sef = dS[1280 + q * 4 + 2];
      double sq  = dS[1280 + q * 4 + 3];
      kl += (float)((((sel - sef) / se) - log(se) + log(sq)) / (double)ns[q]);
    }
    out[802816] = kl;
  }
}

// ===========================================================================
extern "C" void kernel_launch(void* const* d_in, const int* in_sizes, int n_in,
                              void* d_out, int out_size, void* d_ws, size_t ws_size,
                              hipStream_t stream)
{
  const float* x      = (const float*)d_in[0];
  const float* sw_ds  = (const float*)d_in[1];
  const float* sw_c1  = (const float*)d_in[2];
  const float* sw_c2  = (const float*)d_in[3];
  const float* sw_c3  = (const float*)d_in[4];
  const float* a_ds   = (const float*)d_in[5];
  const float* a_c1   = (const float*)d_in[6];
  const float* a_c2   = (const float*)d_in[7];
  const float* a_c3   = (const float*)d_in[8];
  const float* peg_w  = (const float*)d_in[9];
  const float* bn1_g  = (const float*)d_in[10];
  const float* bn1_b  = (const float*)d_in[11];
  const float* bn2_g  = (const float*)d_in[12];
  const float* bn2_b  = (const float*)d_in[13];
  const float* bn3_g  = (const float*)d_in[14];
  const float* bn3_b  = (const float*)d_in[15];
  const float* bnds_g = (const float*)d_in[16];
  const float* bnds_b = (const float*)d_in[17];
  const float* lap_ds = (const float*)d_in[18];
  const float* lap_c1 = (const float*)d_in[19];
  const float* lap_c2 = (const float*)d_in[20];
  const float* lap_c3 = (const float*)d_in[21];

  float* ws    = (float*)d_ws;
  float* f_c2  = ws;                        // 36864
  float* mmbuf = ws + 36864;                // 128
  double* dstat= (double*)(ws + 37120);     // 1344 doubles -> 2688 floats
  float* A     = ws + 39808;                // 802816
  float* T2    = ws + 842624;               // 200704
  float* T3    = ws + 1043328;              // 200704

  float* out = (float*)d_out;

  minmax_kernel<<<64, 256, 0, stream>>>(
      sw_ds, 32768, sw_c1, 8192, sw_c2, 36864, sw_c3, 16384, mmbuf, dstat);

  front_kernel<<<336, 256, 0, stream>>>(
      x, sw_c1, a_c1, lap_c1, sw_c2, a_c2, lap_c2, f_c2,
      sw_c3, a_c3, lap_c3, peg_w, mmbuf, T2, dstat);

  mid_kernel<<<1024, 256, 0, stream>>>(
      x, T2, f_c2, bn1_g, bn1_b, sw_ds, a_ds, lap_ds, mmbuf, T3, A, dstat);

  back_kernel<<<1024, 256, 0, stream>>>(T3, sw_c3, a_c3, mmbuf,
                                        bn2_g, bn2_b, out, dstat);

  final_kernel<<<784, 256, 0, stream>>>(out, A, bn3_g, bn3_b, bnds_g, bnds_b,
                                        dstat);
}

// Round 3
// 172.348 us; speedup vs baseline: 1.0448x; 1.0448x over previous
//
#include <hip/hip_runtime.h>
#include <math.h>

// R7: R5 skeleton (proven 171 us) + rebuilt mid3x3. bnapply_pad restored
// (pre-padded, pre-BN'd T2b makes staging trivial). New mid3x3 stages the
// full 64ch x 9x32 padded window into LDS (73.7 KB, 2 blocks/CU) with
// bounds-check-free float4 copies, then computes the 3x3 L1-adder from LDS
// (replaces R5's 576 scattered global loads/thread and R6's 32x-redundant
// checked staging). 6 kernels:
//   minmax(64) -> front(848: ds, c1+PEG, f_c2, KLt3) -> bnapply(256)
//   -> mid3x3'(512) -> back(1024) -> final(784)

#define HW 784      // 28*28
#define NB 4
#define STAGE 100

// ---------------- wave/block reduction helpers (wave64) --------------------
__device__ __forceinline__ float wredSum(float v){
  for (int o = 32; o > 0; o >>= 1) v += __shfl_down(v, o, 64);
  return v;
}
__device__ __forceinline__ float wredMax(float v){
  for (int o = 32; o > 0; o >>= 1) v = fmaxf(v, __shfl_down(v, o, 64));
  return v;
}
__device__ __forceinline__ float wredMin(float v){
  for (int o = 32; o > 0; o >>= 1) v = fminf(v, __shfl_down(v, o, 64));
  return v;
}
__device__ __forceinline__ double wredSumD(double v){
  for (int o = 32; o > 0; o >>= 1) v += __shfl_down(v, o, 64);
  return v;
}

// blockDim = 256 (4 waves)
__device__ float blockMin4(float v){
  __shared__ float shn[4];
  __syncthreads();
  v = wredMin(v);
  if ((threadIdx.x & 63) == 0) shn[threadIdx.x >> 6] = v;
  __syncthreads();
  return fminf(fminf(shn[0], shn[1]), fminf(shn[2], shn[3]));
}
__device__ float blockMax4(float v){
  __shared__ float shx[4];
  __syncthreads();
  v = wredMax(v);
  if ((threadIdx.x & 63) == 0) shx[threadIdx.x >> 6] = v;
  __syncthreads();
  return fmaxf(fmaxf(shx[0], shx[1]), fmaxf(shx[2], shx[3]));
}

// ---- per-block BN stats: 4 channels, sum+sumsq, double atomics (256 thr) --
__device__ void stats4(float v0, float v1, float v2, float v3,
                       double* sumP, double* sqP, int oc0){
  __shared__ double sred[4][8];
  __syncthreads();
  const int w = threadIdx.x >> 6;
  float vv[4] = {v0, v1, v2, v3};
  #pragma unroll
  for (int i = 0; i < 4; i++){
    double d = (double)vv[i];
    double s = wredSumD(d);
    double q = wredSumD(d * d);
    if ((threadIdx.x & 63) == 0){ sred[w][i] = s; sred[w][4 + i] = q; }
  }
  __syncthreads();
  if (threadIdx.x < 8){
    double tot = sred[0][threadIdx.x] + sred[1][threadIdx.x]
               + sred[2][threadIdx.x] + sred[3][threadIdx.x];
    int i = threadIdx.x & 3;
    if (threadIdx.x < 4) atomicAdd(&sumP[oc0 + i], tot);
    else                 atomicAdd(&sqP[oc0 + i],  tot);
  }
}
__device__ void stats2(float v0, float v1, double* sumP, double* sqP, int oc0){
  __shared__ double sred2[4][4];
  __syncthreads();
  const int w = threadIdx.x >> 6;
  float vv[2] = {v0, v1};
  #pragma unroll
  for (int i = 0; i < 2; i++){
    double d = (double)vv[i];
    double s = wredSumD(d);
    double q = wredSumD(d * d);
    if ((threadIdx.x & 63) == 0){ sred2[w][i] = s; sred2[w][2 + i] = q; }
  }
  __syncthreads();
  if (threadIdx.x < 4){
    double tot = sred2[0][threadIdx.x] + sred2[1][threadIdx.x]
               + sred2[2][threadIdx.x] + sred2[3][threadIdx.x];
    int i = threadIdx.x & 1;
    if (threadIdx.x < 2) atomicAdd(&sumP[oc0 + i], tot);
    else                 atomicAdd(&sqP[oc0 + i],  tot);
  }
}

// ---- KL partial accumulation: 4 sums -> 4 double atomics (256 thr) --------
__device__ void klAccum(float se, float sel, float sef, float sq, double* dst){
  __shared__ double kls[4][4];
  __syncthreads();
  const int w = threadIdx.x >> 6;
  double a0 = wredSumD((double)se);
  double a1 = wredSumD((double)sel);
  double a2 = wredSumD((double)sef);
  double a3 = wredSumD((double)sq);
  if ((threadIdx.x & 63) == 0){
    kls[w][0] = a0; kls[w][1] = a1; kls[w][2] = a2; kls[w][3] = a3;
  }
  __syncthreads();
  if (threadIdx.x < 4){
    double tot = kls[0][threadIdx.x] + kls[1][threadIdx.x]
               + kls[2][threadIdx.x] + kls[3][threadIdx.x];
    atomicAdd(&dst[threadIdx.x], tot);
  }
}

// ---- bin reconstruction (reference op order; exact bin indices) -----------
__device__ __forceinline__ float reconv(float vv, float mn, float rng,
                                        const float* saff){
  float q = (vv - mn) / rng * 100.0f;
  int idx = (int)floorf(q);
  float nv = 0.0f;
  if (idx < STAGE){
    int ci = idx < 0 ? 0 : (idx > STAGE - 1 ? STAGE - 1 : idx);
    nv = vv * saff[ci];
  }
  return nv;
}

// ---- reduce 16 per-block minmax partials (race-free, no atomics) ----------
__device__ __forceinline__ void mmReduce(const float* mmbuf, int tens,
                                         float& mn, float& mx){
  mn = 3.402823466e38f; mx = -3.402823466e38f;
  #pragma unroll
  for (int k = 0; k < 16; k++){
    mn = fminf(mn, mmbuf[tens * 32 + k]);
    mx = fmaxf(mx, mmbuf[tens * 32 + 16 + k]);
  }
}

// --------------- K0: partial min/max of 4 weight tensors + zero stats ------
// grid = 64: tensor = blk>>4, slot = blk&15. Also zeroes dstat (1344 dbl).
// dstat layout: [0:256) ds_sum [256:512) ds_sq [512:576) bn1_s [576:640) bn1_q
//   [640:704) bn2_s [704:768) bn2_q [768:1024) bn3_s [1024:1280) bn3_q
//   [1280:1296) kl: tensor*4 + {se, sel, sef, sq}
__global__ __launch_bounds__(256) void minmax_kernel(
    const float* w0, int n0, const float* w1, int n1,
    const float* w2, int n2, const float* w3, int n3,
    float* mmbuf, double* dstat)
{
  if (threadIdx.x < 21) dstat[blockIdx.x * 21 + threadIdx.x] = 0.0;
  const int tens = blockIdx.x >> 4, slot = blockIdx.x & 15;
  const float* w; int n;
  if      (tens == 0){ w = w0; n = n0; }
  else if (tens == 1){ w = w1; n = n1; }
  else if (tens == 2){ w = w2; n = n2; }
  else               { w = w3; n = n3; }
  float mn = 3.402823466e38f, mx = -3.402823466e38f;
  for (int i = slot * 256 + threadIdx.x; i < n; i += 4096){
    float v = w[i];
    mn = fminf(mn, v); mx = fmaxf(mx, v);
  }
  mn = blockMin4(mn); mx = blockMax4(mx);
  if (threadIdx.x == 0){
    mmbuf[tens * 32 + slot]      = mn;
    mmbuf[tens * 32 + 16 + slot] = mx;
  }
}

// --------------- K1: front — adder_ds + (adder_c1+PEG) + f_c2/KL riders ----
// blocks [0,512): adder_ds, 8 oc, px chunk of 196 (inline recon of slice)
// blocks [512,768): adder_c1+peg, 4 oc, 7-row tile (inline recon)
// blocks [768,832): recon+write f_c2 row (576 elems) + KL partial (t2)
// blocks [832,848): recon f_c3 slice (1024) + KL partial (t3)
__global__ __launch_bounds__(256) void front_kernel(
    const float* __restrict__ x,
    const float* __restrict__ w_ds, const float* __restrict__ aff_ds,
    const float* __restrict__ lap_ds,
    const float* __restrict__ w_c1, const float* __restrict__ aff_c1,
    const float* __restrict__ lap_c1,
    const float* __restrict__ w_c2, const float* __restrict__ aff_c2,
    const float* __restrict__ lap_c2, float* __restrict__ f_c2,
    const float* __restrict__ w_c3, const float* __restrict__ aff_c3,
    const float* __restrict__ lap_c3,
    const float* __restrict__ peg_w, const float* __restrict__ mmbuf,
    float* __restrict__ A, float* __restrict__ T2, double* __restrict__ dS)
{
  const int t = threadIdx.x;
  if (blockIdx.x < 512){
    // ---------------- adder_ds ----------------
    const int a = blockIdx.x;
    const int chunk = a & 3, og = (a >> 2) & 31, b = a >> 7;
    const int oc0 = og * 8;
    __shared__ float saff[STAGE];
    __shared__ float sw[1024];
    if (t < STAGE) saff[t] = aff_ds[t];
    float mn, mx; mmReduce(mmbuf, 0, mn, mx);
    const float rng = mx - mn;
    __syncthreads();
    for (int k = t; k < 1024; k += 256)
      sw[k] = reconv(w_ds[oc0 * 128 + k], mn, rng, saff);
    __syncthreads();

    const int px = chunk * 196 + t;
    float v0=0,v1=0,v2=0,v3=0,v4=0,v5=0,v6=0,v7=0;
    if (t < 196){
      const float* xp = x + (size_t)b * 128 * HW + px;
      float c0=0,c1=0,c2=0,c3=0,c4=0,c5=0,c6=0,c7=0;
      #pragma unroll 4
      for (int c = 0; c < 128; c++){
        float xv = xp[(size_t)c * HW];
        c0 += fabsf(xv - sw[c]);
        c1 += fabsf(xv - sw[128 + c]);
        c2 += fabsf(xv - sw[256 + c]);
        c3 += fabsf(xv - sw[384 + c]);
        c4 += fabsf(xv - sw[512 + c]);
        c5 += fabsf(xv - sw[640 + c]);
        c6 += fabsf(xv - sw[768 + c]);
        c7 += fabsf(xv - sw[896 + c]);
      }
      v0=-c0; v1=-c1; v2=-c2; v3=-c3; v4=-c4; v5=-c5; v6=-c6; v7=-c7;
      float* op = A + ((size_t)(b * 256 + oc0)) * HW + px;
      op[0]=v0; op[HW]=v1; op[2*HW]=v2; op[3*HW]=v3;
      op[4*HW]=v4; op[5*HW]=v5; op[6*HW]=v6; op[7*HW]=v7;
    }
    stats4(v0, v1, v2, v3, dS + 0, dS + 256, oc0);
    stats4(v4, v5, v6, v7, dS + 0, dS + 256, oc0 + 4);

    if (b == 0 && chunk == 0){     // KL partial for tensor 0 (own slice)
      float se = 0, sel = 0, sef = 0, sq = 0;
      for (int k = t; k < 1024; k += 256){
        float l = lap_ds[oc0 * 128 + k];
        float e = expf(l);
        se += e; sel += e * l; sef += e * sw[k];
        sq += expf(sw[k]);
      }
      klAccum(se, sel, sef, sq, dS + 1280 + 0);
    }
  } else if (blockIdx.x < 768){
    // ---------------- adder_c1 + PEG ----------------
    const int a = blockIdx.x - 512;
    const int rc = a & 3, og = (a >> 2) & 15, b = a >> 6;
    const int oc0 = og * 4;
    __shared__ float saffc[STAGE];
    __shared__ float swc[512];
    __shared__ float swp[36];
    __shared__ float sT1[4][256];
    if (t < STAGE) saffc[t] = aff_c1[t];
    if (t >= 128 && t < 164) swp[t - 128] = peg_w[oc0 * 9 + (t - 128)];
    float mn, mx; mmReduce(mmbuf, 1, mn, mx);
    const float rng = mx - mn;
    __syncthreads();
    for (int k = t; k < 512; k += 256)
      swc[k] = reconv(w_c1[oc0 * 128 + k], mn, rng, saffc);
    __syncthreads();

    if (t < 252){
      const int rr = t / 28;
      const int col = t - rr * 28;
      const int wr = rc * 7 - 1 + rr;
      float tv0 = 0, tv1 = 0, tv2 = 0, tv3 = 0;
      if (wr >= 0 && wr < 28){
        const float* xp = x + (size_t)b * 128 * HW + wr * 28 + col;
        float c0 = 0, c1 = 0, c2 = 0, c3 = 0;
        #pragma unroll 4
        for (int c = 0; c < 128; c++){
          float xv = xp[(size_t)c * HW];
          c0 += fabsf(xv - swc[c]);
          c1 += fabsf(xv - swc[128 + c]);
          c2 += fabsf(xv - swc[256 + c]);
          c3 += fabsf(xv - swc[384 + c]);
        }
        tv0 = -c0; tv1 = -c1; tv2 = -c2; tv3 = -c3;
      }
      sT1[0][t] = tv0; sT1[1][t] = tv1; sT1[2][t] = tv2; sT1[3][t] = tv3;
    }
    __syncthreads();
    float v0 = 0, v1 = 0, v2 = 0, v3 = 0;
    if (t < 196){
      const int r = t / 28, col = t - r * 28;
      float c0 = 0, c1 = 0, c2 = 0, c3 = 0;
      #pragma unroll
      for (int ky = 0; ky < 3; ky++){
        #pragma unroll
        for (int kx = 0; kx < 3; kx++){
          int cc = col + kx - 1;
          bool ok = (cc >= 0) && (cc < 28);
          int idx = ok ? ((r + ky) * 28 + cc) : 0;
          float p0 = ok ? sT1[0][idx] : 0.0f;
          float p1 = ok ? sT1[1][idx] : 0.0f;
          float p2 = ok ? sT1[2][idx] : 0.0f;
          float p3 = ok ? sT1[3][idx] : 0.0f;
          int wk = ky * 3 + kx;
          c0 += fabsf(p0 - swp[wk]);
          c1 += fabsf(p1 - swp[9 + wk]);
          c2 += fabsf(p2 - swp[18 + wk]);
          c3 += fabsf(p3 - swp[27 + wk]);
        }
      }
      v0 = -c0; v1 = -c1; v2 = -c2; v3 = -c3;
      const int opx = (rc * 7 + r) * 28 + col;
      float* op = T2 + ((size_t)(b * 64 + oc0)) * HW + opx;
      op[0] = v0; op[HW] = v1; op[2 * HW] = v2; op[3 * HW] = v3;
    }
    stats4(v0, v1, v2, v3, dS + 512, dS + 576, oc0);

    if (b == 0 && rc == 0){        // KL partial for tensor 1
      float se = 0, sel = 0, sef = 0, sq = 0;
      for (int k = t; k < 512; k += 256){
        float l = lap_c1[oc0 * 128 + k];
        float e = expf(l);
        se += e; sel += e * l; sef += e * swc[k];
        sq += expf(swc[k]);
      }
      klAccum(se, sel, sef, sq, dS + 1280 + 4);
    }
  } else if (blockIdx.x < 832){
    // ---------------- f_c2 writer + KL (tensor 2) ----------------
    const int j = blockIdx.x - 768;          // oc row 0..63, 576 elems
    __shared__ float saff2[STAGE];
    if (t < STAGE) saff2[t] = aff_c2[t];
    float mn, mx; mmReduce(mmbuf, 2, mn, mx);
    const float rng = mx - mn;
    __syncthreads();
    float se = 0, sel = 0, sef = 0, sq = 0;
    for (int k = t; k < 576; k += 256){
      float nv = reconv(w_c2[j * 576 + k], mn, rng, saff2);
      f_c2[j * 576 + k] = nv;
      float l = lap_c2[j * 576 + k];
      float e = expf(l);
      se += e; sel += e * l; sef += e * nv; sq += expf(nv);
    }
    klAccum(se, sel, sef, sq, dS + 1280 + 8);
  } else {
    // ---------------- KL (tensor 3) ----------------
    const int j = blockIdx.x - 832;          // slice of 1024
    __shared__ float saff3[STAGE];
    if (t < STAGE) saff3[t] = aff_c3[t];
    float mn, mx; mmReduce(mmbuf, 3, mn, mx);
    const float rng = mx - mn;
    __syncthreads();
    float se = 0, sel = 0, sef = 0, sq = 0;
    for (int k = t; k < 1024; k += 256){
      float nv = reconv(w_c3[j * 1024 + k], mn, rng, saff3);
      float l = lap_c3[j * 1024 + k];
      float e = expf(l);
      se += e; sel += e * l; sef += e * nv; sq += expf(nv);
    }
    klAccum(se, sel, sef, sq, dS + 1280 + 12);
  }
}

// --------------- K2: bn1 finalize + apply + relu -> padded T2b -------------
// T2b: (b, c, row 0..29, col 0..31); interior [1..28]^2 = relu(bn1(T2)).
__global__ __launch_bounds__(256) void bnapply_pad_kernel(
    const float* __restrict__ T2, float* __restrict__ T2b,
    const float* __restrict__ g1, const float* __restrict__ b1,
    const double* __restrict__ dS)
{
  const int a = blockIdx.x;           // b*64 + c
  const int c = a & 63, b = a >> 6;
  __shared__ float ssc, ssb;
  if (threadIdx.x == 0){
    double s  = dS[512 + c] * (1.0 / 3136.0);
    double vr = dS[576 + c] * (1.0 / 3136.0) - s * s;
    float scale = g1[c] * rsqrtf((float)vr + 1e-5f);
    ssc = scale; ssb = b1[c] - (float)s * scale;
  }
  __syncthreads();
  const float sc_ = ssc, bi_ = ssb;
  const float* src = T2 + (size_t)a * HW;
  float* dst = T2b + (size_t)a * 960;
  for (int i = threadIdx.x; i < 960; i += 256){
    int row = i >> 5, col = i & 31;
    float v = 0.0f;
    if (row >= 1 && row <= 28 && col >= 1 && col <= 28)
      v = fmaxf(src[(row - 1) * 28 + (col - 1)] * sc_ + bi_, 0.0f);
    dst[i] = v;
  }
}

// --------------- K3: adder 3x3 from LDS-staged padded T2b ------------------
// Block = (b, og, chunk): stages the full 64ch x 9rows x 32cols window
// (73.7 KB LDS, float4, no bounds checks -- T2b is pre-padded) then computes
// 2 oc x 196 px from LDS. 2 blocks/CU.
__global__ __launch_bounds__(256) void mid3x3_kernel(
    const float* __restrict__ T2b, const float* __restrict__ f_c2,
    float* __restrict__ T3, double* __restrict__ dS)
{
  const int t = threadIdx.x;
  const int a = blockIdx.x;
  const int chunk = a & 3, og = (a >> 2) & 31, b = a >> 7;
  const int oc0 = og * 2;
  __shared__ float sT[64 * 288];           // [c][rr 0..8][cl 0..31]

  // stage: window rows (chunk*7 .. chunk*7+8) of padded 30x32 image, 64 ch.
  // 288 floats = 72 float4 per channel; 4608 float4 total = 18 per thread.
  const float* src = T2b + (size_t)b * 64 * 960 + chunk * 224;
  float4* s4 = (float4*)sT;
  #pragma unroll
  for (int q = 0; q < 18; q++){
    int flat = q * 256 + t;                // 0..4607
    int c = flat / 72;
    int w = flat - c * 72;
    s4[flat] = *(const float4*)(src + (size_t)c * 960 + w * 4);
  }
  __syncthreads();

  const float* __restrict__ wA = f_c2 + oc0 * 576;
  const float* __restrict__ wB = wA + 576;
  float v0 = 0.0f, v1 = 0.0f;
  if (t < 196){
    const int r = t / 28, col = t - r * 28;
    const float* pbase = sT + r * 32 + col;
    float c0 = 0.0f, c1 = 0.0f;
    #pragma unroll 4
    for (int c = 0; c < 64; c++){
      const float* p = pbase + c * 288;
      float t0 = p[0],  t1 = p[1],  t2 = p[2];
      float t3 = p[32], t4 = p[33], t5 = p[34];
      float t6 = p[64], t7 = p[65], t8 = p[66];
      const float* wa = wA + c * 9;
      const float* wb = wB + c * 9;
      c0 += fabsf(t0 - wa[0]) + fabsf(t1 - wa[1]) + fabsf(t2 - wa[2])
          + fabsf(t3 - wa[3]) + fabsf(t4 - wa[4]) + fabsf(t5 - wa[5])
          + fabsf(t6 - wa[6]) + fabsf(t7 - wa[7]) + fabsf(t8 - wa[8]);
      c1 += fabsf(t0 - wb[0]) + fabsf(t1 - wb[1]) + fabsf(t2 - wb[2])
          + fabsf(t3 - wb[3]) + fabsf(t4 - wb[4]) + fabsf(t5 - wb[5])
          + fabsf(t6 - wb[6]) + fabsf(t7 - wb[7]) + fabsf(t8 - wb[8]);
    }
    v0 = -c0; v1 = -c1;
    const int px = chunk * 196 + t;
    T3[((size_t)(b * 64 + oc0)) * HW + px]     = v0;
    T3[((size_t)(b * 64 + oc0 + 1)) * HW + px] = v1;
  }
  stats2(v0, v1, dS + 640, dS + 704, oc0);
}

// --------------- K4: adder 1x1 64->256 (bn2 inline, inline recon) ----------
__global__ __launch_bounds__(256) void back_kernel(
    const float* __restrict__ T3, const float* __restrict__ w_c3,
    const float* __restrict__ aff_c3, const float* __restrict__ mmbuf,
    const float* __restrict__ g2, const float* __restrict__ b2,
    float* __restrict__ out, double* __restrict__ dS)
{
  const int t = threadIdx.x;
  const int a = blockIdx.x;
  const int chunk = a & 3, og = (a >> 2) & 63, b = a >> 8;
  const int oc0 = og * 4;
  __shared__ float ssc[64], ssb[64], sw[256], saff[STAGE];
  if (t < 64){
    double s  = dS[640 + t] * (1.0 / 3136.0);
    double vr = dS[704 + t] * (1.0 / 3136.0) - s * s;
    float scale = g2[t] * rsqrtf((float)vr + 1e-5f);
    ssc[t] = scale; ssb[t] = b2[t] - (float)s * scale;
  }
  if (t >= 128 && t < 128 + STAGE) saff[t - 128] = aff_c3[t - 128];
  float mn, mx; mmReduce(mmbuf, 3, mn, mx);
  const float rng = mx - mn;
  __syncthreads();
  sw[t] = reconv(w_c3[oc0 * 64 + t], mn, rng, saff);
  __syncthreads();

  const int px = chunk * 196 + t;
  float v0 = 0, v1 = 0, v2 = 0, v3 = 0;
  if (t < 196){
    const float* bp = T3 + (size_t)b * 64 * HW + px;
    float c0 = 0, c1 = 0, c2 = 0, c3 = 0;
    #pragma unroll 4
    for (int c = 0; c < 64; c++){
      float raw = bp[(size_t)c * HW];
      float vv = fmaxf(raw * ssc[c] + ssb[c], 0.0f);
      c0 += fabsf(vv - sw[c]);
      c1 += fabsf(vv - sw[64 + c]);
      c2 += fabsf(vv - sw[128 + c]);
      c3 += fabsf(vv - sw[192 + c]);
    }
    v0 = -c0; v1 = -c1; v2 = -c2; v3 = -c3;
    float* op = out + ((size_t)(b * 256 + oc0)) * HW + px;
    op[0] = v0; op[HW] = v1; op[2 * HW] = v2; op[3 * HW] = v3;
  }
  stats4(v0, v1, v2, v3, dS + 768, dS + 1024, oc0);
}

// --------------- K5: bn3 + bnds finalize, residual, relu, kl ---------------
__global__ __launch_bounds__(256) void final_kernel(
    float* __restrict__ out, const float* __restrict__ A,
    const float* __restrict__ g3, const float* __restrict__ b3,
    const float* __restrict__ gds, const float* __restrict__ bds,
    const double* __restrict__ dS)
{
  __shared__ float s3c[256], s3b[256], sdc[256], sdb[256];
  const int t = threadIdx.x;
  {
    double s  = dS[768 + t] * (1.0 / 3136.0);
    double vr = dS[1024 + t] * (1.0 / 3136.0) - s * s;
    float scale = g3[t] * rsqrtf((float)vr + 1e-5f);
    s3c[t] = scale; s3b[t] = b3[t] - (float)s * scale;
    s  = dS[t] * (1.0 / 3136.0);
    vr = dS[256 + t] * (1.0 / 3136.0) - s * s;
    scale = gds[t] * rsqrtf((float)vr + 1e-5f);
    sdc[t] = scale; sdb[t] = bds[t] - (float)s * scale;
  }
  __syncthreads();
  #pragma unroll
  for (int k = 0; k < 4; k++){
    int n = blockIdx.x * 1024 + k * 256 + t;
    int c = (n / HW) & 255;
    float h = out[n], aa = A[n];
    float r = fmaxf(aa * sdc[c] + sdb[c], 0.0f);
    out[n] = fmaxf(h * s3c[c] + s3b[c] + r, 0.0f);
  }
  if (blockIdx.x == 0 && t == 0){
    const int ns[4] = {32768, 8192, 36864, 16384};
    float kl = 0.0f;
    #pragma unroll
    for (int q = 0; q < 4; q++){
      double se  = dS[1280 + q * 4];
      double sel = dS[1280 + q * 4 + 1];
      double sef = dS[1280 + q * 4 + 2];
      double sq  = dS[1280 + q * 4 + 3];
      kl += (float)((((sel - sef) / se) - log(se) + log(sq)) / (double)ns[q]);
    }
    out[802816] = kl;
  }
}

// ===========================================================================
extern "C" void kernel_launch(void* const* d_in, const int* in_sizes, int n_in,
                              void* d_out, int out_size, void* d_ws, size_t ws_size,
                              hipStream_t stream)
{
  const float* x      = (const float*)d_in[0];
  const float* sw_ds  = (const float*)d_in[1];
  const float* sw_c1  = (const float*)d_in[2];
  const float* sw_c2  = (const float*)d_in[3];
  const float* sw_c3  = (const float*)d_in[4];
  const float* a_ds   = (const float*)d_in[5];
  const float* a_c1   = (const float*)d_in[6];
  const float* a_c2   = (const float*)d_in[7];
  const float* a_c3   = (const float*)d_in[8];
  const float* peg_w  = (const float*)d_in[9];
  const float* bn1_g  = (const float*)d_in[10];
  const float* bn1_b  = (const float*)d_in[11];
  const float* bn2_g  = (const float*)d_in[12];
  const float* bn2_b  = (const float*)d_in[13];
  const float* bn3_g  = (const float*)d_in[14];
  const float* bn3_b  = (const float*)d_in[15];
  const float* bnds_g = (const float*)d_in[16];
  const float* bnds_b = (const float*)d_in[17];
  const float* lap_ds = (const float*)d_in[18];
  const float* lap_c1 = (const float*)d_in[19];
  const float* lap_c2 = (const float*)d_in[20];
  const float* lap_c3 = (const float*)d_in[21];

  float* ws    = (float*)d_ws;
  float* f_c2  = ws;                        // 36864
  float* mmbuf = ws + 36864;                // 128
  double* dstat= (double*)(ws + 37120);     // 1344 doubles -> 2688 floats
  float* A     = ws + 39808;                // 802816
  float* T2    = ws + 842624;               // 200704
  float* T3    = ws + 1043328;              // 200704
  float* T2b   = ws + 1244032;              // 245760

  float* out = (float*)d_out;

  minmax_kernel<<<64, 256, 0, stream>>>(
      sw_ds, 32768, sw_c1, 8192, sw_c2, 36864, sw_c3, 16384, mmbuf, dstat);

  front_kernel<<<848, 256, 0, stream>>>(
      x, sw_ds, a_ds, lap_ds, sw_c1, a_c1, lap_c1,
      sw_c2, a_c2, lap_c2, f_c2, sw_c3, a_c3, lap_c3,
      peg_w, mmbuf, A, T2, dstat);

  bnapply_pad_kernel<<<256, 256, 0, stream>>>(T2, T2b, bn1_g, bn1_b, dstat);

  mid3x3_kernel<<<512, 256, 0, stream>>>(T2b, f_c2, T3, dstat);

  back_kernel<<<1024, 256, 0, stream>>>(T3, sw_c3, a_c3, mmbuf,
                                        bn2_g, bn2_b, out, dstat);

  final_kernel<<<784, 256, 0, stream>>>(out, A, bn3_g, bn3_b, bnds_g, bnds_b,
                                        dstat);
}

// Round 4
// 170.118 us; speedup vs baseline: 1.0585x; 1.0131x over previous
//
#include <hip/hip_runtime.h>
#include <math.h>

// R8: kill bnapply_pad (6->5 kernels). front c1-blocks now write raw PEG
// output directly into padded T2b layout (and zero the border cells they
// own); mid3x3 applies BN1+relu during its float4 LDS staging (per-lane
// interior predicate keeps borders 0). Everything else identical to R7.
//   minmax(64) -> front(848, writes padded raw T2b) -> mid3x3(512, BN in
//   staging) -> back(1024) -> final(784)

#define HW 784      // 28*28
#define NB 4
#define STAGE 100

// ---------------- wave/block reduction helpers (wave64) --------------------
__device__ __forceinline__ float wredSum(float v){
  for (int o = 32; o > 0; o >>= 1) v += __shfl_down(v, o, 64);
  return v;
}
__device__ __forceinline__ float wredMax(float v){
  for (int o = 32; o > 0; o >>= 1) v = fmaxf(v, __shfl_down(v, o, 64));
  return v;
}
__device__ __forceinline__ float wredMin(float v){
  for (int o = 32; o > 0; o >>= 1) v = fminf(v, __shfl_down(v, o, 64));
  return v;
}
__device__ __forceinline__ double wredSumD(double v){
  for (int o = 32; o > 0; o >>= 1) v += __shfl_down(v, o, 64);
  return v;
}

// blockDim = 256 (4 waves)
__device__ float blockMin4(float v){
  __shared__ float shn[4];
  __syncthreads();
  v = wredMin(v);
  if ((threadIdx.x & 63) == 0) shn[threadIdx.x >> 6] = v;
  __syncthreads();
  return fminf(fminf(shn[0], shn[1]), fminf(shn[2], shn[3]));
}
__device__ float blockMax4(float v){
  __shared__ float shx[4];
  __syncthreads();
  v = wredMax(v);
  if ((threadIdx.x & 63) == 0) shx[threadIdx.x >> 6] = v;
  __syncthreads();
  return fmaxf(fmaxf(shx[0], shx[1]), fmaxf(shx[2], shx[3]));
}

// ---- per-block BN stats: 4 channels, sum+sumsq, double atomics (256 thr) --
__device__ void stats4(float v0, float v1, float v2, float v3,
                       double* sumP, double* sqP, int oc0){
  __shared__ double sred[4][8];
  __syncthreads();
  const int w = threadIdx.x >> 6;
  float vv[4] = {v0, v1, v2, v3};
  #pragma unroll
  for (int i = 0; i < 4; i++){
    double d = (double)vv[i];
    double s = wredSumD(d);
    double q = wredSumD(d * d);
    if ((threadIdx.x & 63) == 0){ sred[w][i] = s; sred[w][4 + i] = q; }
  }
  __syncthreads();
  if (threadIdx.x < 8){
    double tot = sred[0][threadIdx.x] + sred[1][threadIdx.x]
               + sred[2][threadIdx.x] + sred[3][threadIdx.x];
    int i = threadIdx.x & 3;
    if (threadIdx.x < 4) atomicAdd(&sumP[oc0 + i], tot);
    else                 atomicAdd(&sqP[oc0 + i],  tot);
  }
}
__device__ void stats2(float v0, float v1, double* sumP, double* sqP, int oc0){
  __shared__ double sred2[4][4];
  __syncthreads();
  const int w = threadIdx.x >> 6;
  float vv[2] = {v0, v1};
  #pragma unroll
  for (int i = 0; i < 2; i++){
    double d = (double)vv[i];
    double s = wredSumD(d);
    double q = wredSumD(d * d);
    if ((threadIdx.x & 63) == 0){ sred2[w][i] = s; sred2[w][2 + i] = q; }
  }
  __syncthreads();
  if (threadIdx.x < 4){
    double tot = sred2[0][threadIdx.x] + sred2[1][threadIdx.x]
               + sred2[2][threadIdx.x] + sred2[3][threadIdx.x];
    int i = threadIdx.x & 1;
    if (threadIdx.x < 2) atomicAdd(&sumP[oc0 + i], tot);
    else                 atomicAdd(&sqP[oc0 + i],  tot);
  }
}

// ---- KL partial accumulation: 4 sums -> 4 double atomics (256 thr) --------
__device__ void klAccum(float se, float sel, float sef, float sq, double* dst){
  __shared__ double kls[4][4];
  __syncthreads();
  const int w = threadIdx.x >> 6;
  double a0 = wredSumD((double)se);
  double a1 = wredSumD((double)sel);
  double a2 = wredSumD((double)sef);
  double a3 = wredSumD((double)sq);
  if ((threadIdx.x & 63) == 0){
    kls[w][0] = a0; kls[w][1] = a1; kls[w][2] = a2; kls[w][3] = a3;
  }
  __syncthreads();
  if (threadIdx.x < 4){
    double tot = kls[0][threadIdx.x] + kls[1][threadIdx.x]
               + kls[2][threadIdx.x] + kls[3][threadIdx.x];
    atomicAdd(&dst[threadIdx.x], tot);
  }
}

// ---- bin reconstruction (reference op order; exact bin indices) -----------
__device__ __forceinline__ float reconv(float vv, float mn, float rng,
                                        const float* saff){
  float q = (vv - mn) / rng * 100.0f;
  int idx = (int)floorf(q);
  float nv = 0.0f;
  if (idx < STAGE){
    int ci = idx < 0 ? 0 : (idx > STAGE - 1 ? STAGE - 1 : idx);
    nv = vv * saff[ci];
  }
  return nv;
}

// ---- reduce 16 per-block minmax partials (race-free, no atomics) ----------
__device__ __forceinline__ void mmReduce(const float* mmbuf, int tens,
                                         float& mn, float& mx){
  mn = 3.402823466e38f; mx = -3.402823466e38f;
  #pragma unroll
  for (int k = 0; k < 16; k++){
    mn = fminf(mn, mmbuf[tens * 32 + k]);
    mx = fmaxf(mx, mmbuf[tens * 32 + 16 + k]);
  }
}

// --------------- K0: partial min/max of 4 weight tensors + zero stats ------
// grid = 64: tensor = blk>>4, slot = blk&15. Also zeroes dstat (1344 dbl).
// dstat layout: [0:256) ds_sum [256:512) ds_sq [512:576) bn1_s [576:640) bn1_q
//   [640:704) bn2_s [704:768) bn2_q [768:1024) bn3_s [1024:1280) bn3_q
//   [1280:1296) kl: tensor*4 + {se, sel, sef, sq}
__global__ __launch_bounds__(256) void minmax_kernel(
    const float* w0, int n0, const float* w1, int n1,
    const float* w2, int n2, const float* w3, int n3,
    float* mmbuf, double* dstat)
{
  if (threadIdx.x < 21) dstat[blockIdx.x * 21 + threadIdx.x] = 0.0;
  const int tens = blockIdx.x >> 4, slot = blockIdx.x & 15;
  const float* w; int n;
  if      (tens == 0){ w = w0; n = n0; }
  else if (tens == 1){ w = w1; n = n1; }
  else if (tens == 2){ w = w2; n = n2; }
  else               { w = w3; n = n3; }
  float mn = 3.402823466e38f, mx = -3.402823466e38f;
  for (int i = slot * 256 + threadIdx.x; i < n; i += 4096){
    float v = w[i];
    mn = fminf(mn, v); mx = fmaxf(mx, v);
  }
  mn = blockMin4(mn); mx = blockMax4(mx);
  if (threadIdx.x == 0){
    mmbuf[tens * 32 + slot]      = mn;
    mmbuf[tens * 32 + 16 + slot] = mx;
  }
}

// --------------- K1: front — adder_ds + (adder_c1+PEG) + f_c2/KL riders ----
// blocks [0,512): adder_ds, 8 oc, px chunk of 196 (inline recon of slice)
// blocks [512,768): adder_c1+peg, 4 oc, 7-row tile; writes RAW values into
//                   padded T2b (prow=wr+1, pcol=col+1) + zeroes its border
// blocks [768,832): recon+write f_c2 row (576 elems) + KL partial (t2)
// blocks [832,848): recon f_c3 slice (1024) + KL partial (t3)
__global__ __launch_bounds__(256) void front_kernel(
    const float* __restrict__ x,
    const float* __restrict__ w_ds, const float* __restrict__ aff_ds,
    const float* __restrict__ lap_ds,
    const float* __restrict__ w_c1, const float* __restrict__ aff_c1,
    const float* __restrict__ lap_c1,
    const float* __restrict__ w_c2, const float* __restrict__ aff_c2,
    const float* __restrict__ lap_c2, float* __restrict__ f_c2,
    const float* __restrict__ w_c3, const float* __restrict__ aff_c3,
    const float* __restrict__ lap_c3,
    const float* __restrict__ peg_w, const float* __restrict__ mmbuf,
    float* __restrict__ A, float* __restrict__ T2b, double* __restrict__ dS)
{
  const int t = threadIdx.x;
  if (blockIdx.x < 512){
    // ---------------- adder_ds ----------------
    const int a = blockIdx.x;
    const int chunk = a & 3, og = (a >> 2) & 31, b = a >> 7;
    const int oc0 = og * 8;
    __shared__ float saff[STAGE];
    __shared__ float sw[1024];
    if (t < STAGE) saff[t] = aff_ds[t];
    float mn, mx; mmReduce(mmbuf, 0, mn, mx);
    const float rng = mx - mn;
    __syncthreads();
    for (int k = t; k < 1024; k += 256)
      sw[k] = reconv(w_ds[oc0 * 128 + k], mn, rng, saff);
    __syncthreads();

    const int px = chunk * 196 + t;
    float v0=0,v1=0,v2=0,v3=0,v4=0,v5=0,v6=0,v7=0;
    if (t < 196){
      const float* xp = x + (size_t)b * 128 * HW + px;
      float c0=0,c1=0,c2=0,c3=0,c4=0,c5=0,c6=0,c7=0;
      #pragma unroll 4
      for (int c = 0; c < 128; c++){
        float xv = xp[(size_t)c * HW];
        c0 += fabsf(xv - sw[c]);
        c1 += fabsf(xv - sw[128 + c]);
        c2 += fabsf(xv - sw[256 + c]);
        c3 += fabsf(xv - sw[384 + c]);
        c4 += fabsf(xv - sw[512 + c]);
        c5 += fabsf(xv - sw[640 + c]);
        c6 += fabsf(xv - sw[768 + c]);
        c7 += fabsf(xv - sw[896 + c]);
      }
      v0=-c0; v1=-c1; v2=-c2; v3=-c3; v4=-c4; v5=-c5; v6=-c6; v7=-c7;
      float* op = A + ((size_t)(b * 256 + oc0)) * HW + px;
      op[0]=v0; op[HW]=v1; op[2*HW]=v2; op[3*HW]=v3;
      op[4*HW]=v4; op[5*HW]=v5; op[6*HW]=v6; op[7*HW]=v7;
    }
    stats4(v0, v1, v2, v3, dS + 0, dS + 256, oc0);
    stats4(v4, v5, v6, v7, dS + 0, dS + 256, oc0 + 4);

    if (b == 0 && chunk == 0){     // KL partial for tensor 0 (own slice)
      float se = 0, sel = 0, sef = 0, sq = 0;
      for (int k = t; k < 1024; k += 256){
        float l = lap_ds[oc0 * 128 + k];
        float e = expf(l);
        se += e; sel += e * l; sef += e * sw[k];
        sq += expf(sw[k]);
      }
      klAccum(se, sel, sef, sq, dS + 1280 + 0);
    }
  } else if (blockIdx.x < 768){
    // ---------------- adder_c1 + PEG -> padded raw T2b ----------------
    const int a = blockIdx.x - 512;
    const int rc = a & 3, og = (a >> 2) & 15, b = a >> 6;
    const int oc0 = og * 4;
    __shared__ float saffc[STAGE];
    __shared__ float swc[512];
    __shared__ float swp[36];
    __shared__ float sT1[4][256];
    if (t < STAGE) saffc[t] = aff_c1[t];
    if (t >= 128 && t < 164) swp[t - 128] = peg_w[oc0 * 9 + (t - 128)];
    float mn, mx; mmReduce(mmbuf, 1, mn, mx);
    const float rng = mx - mn;
    __syncthreads();
    for (int k = t; k < 512; k += 256)
      swc[k] = reconv(w_c1[oc0 * 128 + k], mn, rng, saffc);

    // border zeros for the rows this block owns (raw T2b must be 0 there)
    {
      float* tb = T2b + (size_t)(b * 64 + oc0) * 960;
      // side cols {0,29,30,31} at prows rc*7+1 .. rc*7+7, 4 channels
      for (int i = t; i < 112; i += 256){
        int ch = i / 28;
        int j  = i - ch * 28;
        int r7 = j >> 2, cs = j & 3;
        int col = (cs == 0) ? 0 : 28 + cs;
        tb[(size_t)ch * 960 + (rc * 7 + 1 + r7) * 32 + col] = 0.0f;
      }
      if (rc == 0){               // full prow 0
        for (int i = t; i < 128; i += 256){
          int ch = i >> 5, col = i & 31;
          tb[(size_t)ch * 960 + col] = 0.0f;
        }
      }
      if (rc == 3){               // full prow 29
        for (int i = t; i < 128; i += 256){
          int ch = i >> 5, col = i & 31;
          tb[(size_t)ch * 960 + 29 * 32 + col] = 0.0f;
        }
      }
    }
    __syncthreads();

    if (t < 252){
      const int rr = t / 28;
      const int col = t - rr * 28;
      const int wr = rc * 7 - 1 + rr;
      float tv0 = 0, tv1 = 0, tv2 = 0, tv3 = 0;
      if (wr >= 0 && wr < 28){
        const float* xp = x + (size_t)b * 128 * HW + wr * 28 + col;
        float c0 = 0, c1 = 0, c2 = 0, c3 = 0;
        #pragma unroll 4
        for (int c = 0; c < 128; c++){
          float xv = xp[(size_t)c * HW];
          c0 += fabsf(xv - swc[c]);
          c1 += fabsf(xv - swc[128 + c]);
          c2 += fabsf(xv - swc[256 + c]);
          c3 += fabsf(xv - swc[384 + c]);
        }
        tv0 = -c0; tv1 = -c1; tv2 = -c2; tv3 = -c3;
      }
      sT1[0][t] = tv0; sT1[1][t] = tv1; sT1[2][t] = tv2; sT1[3][t] = tv3;
    }
    __syncthreads();
    float v0 = 0, v1 = 0, v2 = 0, v3 = 0;
    if (t < 196){
      const int r = t / 28, col = t - r * 28;
      float c0 = 0, c1 = 0, c2 = 0, c3 = 0;
      #pragma unroll
      for (int ky = 0; ky < 3; ky++){
        #pragma unroll
        for (int kx = 0; kx < 3; kx++){
          int cc = col + kx - 1;
          bool ok = (cc >= 0) && (cc < 28);
          int idx = ok ? ((r + ky) * 28 + cc) : 0;
          float p0 = ok ? sT1[0][idx] : 0.0f;
          float p1 = ok ? sT1[1][idx] : 0.0f;
          float p2 = ok ? sT1[2][idx] : 0.0f;
          float p3 = ok ? sT1[3][idx] : 0.0f;
          int wk = ky * 3 + kx;
          c0 += fabsf(p0 - swp[wk]);
          c1 += fabsf(p1 - swp[9 + wk]);
          c2 += fabsf(p2 - swp[18 + wk]);
          c3 += fabsf(p3 - swp[27 + wk]);
        }
      }
      v0 = -c0; v1 = -c1; v2 = -c2; v3 = -c3;
      const int prow = rc * 7 + r + 1;
      float* op = T2b + (size_t)(b * 64 + oc0) * 960 + prow * 32 + (col + 1);
      op[0] = v0; op[960] = v1; op[1920] = v2; op[2880] = v3;
    }
    stats4(v0, v1, v2, v3, dS + 512, dS + 576, oc0);

    if (b == 0 && rc == 0){        // KL partial for tensor 1
      float se = 0, sel = 0, sef = 0, sq = 0;
      for (int k = t; k < 512; k += 256){
        float l = lap_c1[oc0 * 128 + k];
        float e = expf(l);
        se += e; sel += e * l; sef += e * swc[k];
        sq += expf(swc[k]);
      }
      klAccum(se, sel, sef, sq, dS + 1280 + 4);
    }
  } else if (blockIdx.x < 832){
    // ---------------- f_c2 writer + KL (tensor 2) ----------------
    const int j = blockIdx.x - 768;          // oc row 0..63, 576 elems
    __shared__ float saff2[STAGE];
    if (t < STAGE) saff2[t] = aff_c2[t];
    float mn, mx; mmReduce(mmbuf, 2, mn, mx);
    const float rng = mx - mn;
    __syncthreads();
    float se = 0, sel = 0, sef = 0, sq = 0;
    for (int k = t; k < 576; k += 256){
      float nv = reconv(w_c2[j * 576 + k], mn, rng, saff2);
      f_c2[j * 576 + k] = nv;
      float l = lap_c2[j * 576 + k];
      float e = expf(l);
      se += e; sel += e * l; sef += e * nv; sq += expf(nv);
    }
    klAccum(se, sel, sef, sq, dS + 1280 + 8);
  } else {
    // ---------------- KL (tensor 3) ----------------
    const int j = blockIdx.x - 832;          // slice of 1024
    __shared__ float saff3[STAGE];
    if (t < STAGE) saff3[t] = aff_c3[t];
    float mn, mx; mmReduce(mmbuf, 3, mn, mx);
    const float rng = mx - mn;
    __syncthreads();
    float se = 0, sel = 0, sef = 0, sq = 0;
    for (int k = t; k < 1024; k += 256){
      float nv = reconv(w_c3[j * 1024 + k], mn, rng, saff3);
      float l = lap_c3[j * 1024 + k];
      float e = expf(l);
      se += e; sel += e * l; sef += e * nv; sq += expf(nv);
    }
    klAccum(se, sel, sef, sq, dS + 1280 + 12);
  }
}

// --------------- K2: adder 3x3; BN1 fused into float4 LDS staging ----------
// Block = (b, og, chunk): stage 64ch x 9rows x 32cols window of RAW T2b,
// applying relu(raw*sc+sb) to interior elements (border lanes -> 0), then
// compute 2 oc x 196 px from LDS. 73.7 KB LDS, 2 blocks/CU.
__global__ __launch_bounds__(256) void mid3x3_kernel(
    const float* __restrict__ T2b, const float* __restrict__ f_c2,
    const float* __restrict__ g1, const float* __restrict__ b1,
    float* __restrict__ T3, double* __restrict__ dS)
{
  const int t = threadIdx.x;
  const int a = blockIdx.x;
  const int chunk = a & 3, og = (a >> 2) & 31, b = a >> 7;
  const int oc0 = og * 2;
  __shared__ float sT[64 * 288];           // [c][rr 0..8][cl 0..31]
  __shared__ float ssc[64], ssb[64];

  if (t < 64){
    double s  = dS[512 + t] * (1.0 / 3136.0);
    double vr = dS[576 + t] * (1.0 / 3136.0) - s * s;
    float scale = g1[t] * rsqrtf((float)vr + 1e-5f);
    ssc[t] = scale; ssb[t] = b1[t] - (float)s * scale;
  }
  __syncthreads();

  // stage: window rows (chunk*7 .. chunk*7+8) of padded 30x32 image, 64 ch.
  // 288 floats = 72 float4 per channel; 4608 float4 total = 18 per thread.
  const float* src = T2b + (size_t)b * 64 * 960 + chunk * 224;
  float4* s4 = (float4*)sT;
  #pragma unroll
  for (int q = 0; q < 18; q++){
    int flat = q * 256 + t;                // 0..4607
    int c = flat / 72;
    int w = flat - c * 72;
    float4 v = *(const float4*)(src + (size_t)c * 960 + w * 4);
    int rr = w >> 3;                       // 0..8
    int prow = chunk * 7 + rr;             // padded row 0..29
    bool rok = (prow >= 1) && (prow <= 28);
    int pc0 = (w & 7) * 4;                 // padded col of v.x
    float sc = ssc[c], sb = ssb[c];
    v.x = (rok && pc0     >= 1 && pc0     <= 28) ? fmaxf(v.x * sc + sb, 0.f) : 0.f;
    v.y = (rok && pc0 + 1 >= 1 && pc0 + 1 <= 28) ? fmaxf(v.y * sc + sb, 0.f) : 0.f;
    v.z = (rok && pc0 + 2 >= 1 && pc0 + 2 <= 28) ? fmaxf(v.z * sc + sb, 0.f) : 0.f;
    v.w = (rok && pc0 + 3 >= 1 && pc0 + 3 <= 28) ? fmaxf(v.w * sc + sb, 0.f) : 0.f;
    s4[flat] = v;
  }
  __syncthreads();

  const float* __restrict__ wA = f_c2 + oc0 * 576;
  const float* __restrict__ wB = wA + 576;
  float v0 = 0.0f, v1 = 0.0f;
  if (t < 196){
    const int r = t / 28, col = t - r * 28;
    const float* pbase = sT + r * 32 + col;
    float c0 = 0.0f, c1 = 0.0f;
    #pragma unroll 4
    for (int c = 0; c < 64; c++){
      const float* p = pbase + c * 288;
      float t0 = p[0],  t1 = p[1],  t2 = p[2];
      float t3 = p[32], t4 = p[33], t5 = p[34];
      float t6 = p[64], t7 = p[65], t8 = p[66];
      const float* wa = wA + c * 9;
      const float* wb = wB + c * 9;
      c0 += fabsf(t0 - wa[0]) + fabsf(t1 - wa[1]) + fabsf(t2 - wa[2])
          + fabsf(t3 - wa[3]) + fabsf(t4 - wa[4]) + fabsf(t5 - wa[5])
          + fabsf(t6 - wa[6]) + fabsf(t7 - wa[7]) + fabsf(t8 - wa[8]);
      c1 += fabsf(t0 - wb[0]) + fabsf(t1 - wb[1]) + fabsf(t2 - wb[2])
          + fabsf(t3 - wb[3]) + fabsf(t4 - wb[4]) + fabsf(t5 - wb[5])
          + fabsf(t6 - wb[6]) + fabsf(t7 - wb[7]) + fabsf(t8 - wb[8]);
    }
    v0 = -c0; v1 = -c1;
    const int px = chunk * 196 + t;
    T3[((size_t)(b * 64 + oc0)) * HW + px]     = v0;
    T3[((size_t)(b * 64 + oc0 + 1)) * HW + px] = v1;
  }
  stats2(v0, v1, dS + 640, dS + 704, oc0);
}

// --------------- K3: adder 1x1 64->256 (bn2 inline, inline recon) ----------
__global__ __launch_bounds__(256) void back_kernel(
    const float* __restrict__ T3, const float* __restrict__ w_c3,
    const float* __restrict__ aff_c3, const float* __restrict__ mmbuf,
    const float* __restrict__ g2, const float* __restrict__ b2,
    float* __restrict__ out, double* __restrict__ dS)
{
  const int t = threadIdx.x;
  const int a = blockIdx.x;
  const int chunk = a & 3, og = (a >> 2) & 63, b = a >> 8;
  const int oc0 = og * 4;
  __shared__ float ssc[64], ssb[64], sw[256], saff[STAGE];
  if (t < 64){
    double s  = dS[640 + t] * (1.0 / 3136.0);
    double vr = dS[704 + t] * (1.0 / 3136.0) - s * s;
    float scale = g2[t] * rsqrtf((float)vr + 1e-5f);
    ssc[t] = scale; ssb[t] = b2[t] - (float)s * scale;
  }
  if (t >= 128 && t < 128 + STAGE) saff[t - 128] = aff_c3[t - 128];
  float mn, mx; mmReduce(mmbuf, 3, mn, mx);
  const float rng = mx - mn;
  __syncthreads();
  sw[t] = reconv(w_c3[oc0 * 64 + t], mn, rng, saff);
  __syncthreads();

  const int px = chunk * 196 + t;
  float v0 = 0, v1 = 0, v2 = 0, v3 = 0;
  if (t < 196){
    const float* bp = T3 + (size_t)b * 64 * HW + px;
    float c0 = 0, c1 = 0, c2 = 0, c3 = 0;
    #pragma unroll 4
    for (int c = 0; c < 64; c++){
      float raw = bp[(size_t)c * HW];
      float vv = fmaxf(raw * ssc[c] + ssb[c], 0.0f);
      c0 += fabsf(vv - sw[c]);
      c1 += fabsf(vv - sw[64 + c]);
      c2 += fabsf(vv - sw[128 + c]);
      c3 += fabsf(vv - sw[192 + c]);
    }
    v0 = -c0; v1 = -c1; v2 = -c2; v3 = -c3;
    float* op = out + ((size_t)(b * 256 + oc0)) * HW + px;
    op[0] = v0; op[HW] = v1; op[2 * HW] = v2; op[3 * HW] = v3;
  }
  stats4(v0, v1, v2, v3, dS + 768, dS + 1024, oc0);
}

// --------------- K4: bn3 + bnds finalize, residual, relu, kl ---------------
__global__ __launch_bounds__(256) void final_kernel(
    float* __restrict__ out, const float* __restrict__ A,
    const float* __restrict__ g3, const float* __restrict__ b3,
    const float* __restrict__ gds, const float* __restrict__ bds,
    const double* __restrict__ dS)
{
  __shared__ float s3c[256], s3b[256], sdc[256], sdb[256];
  const int t = threadIdx.x;
  {
    double s  = dS[768 + t] * (1.0 / 3136.0);
    double vr = dS[1024 + t] * (1.0 / 3136.0) - s * s;
    float scale = g3[t] * rsqrtf((float)vr + 1e-5f);
    s3c[t] = scale; s3b[t] = b3[t] - (float)s * scale;
    s  = dS[t] * (1.0 / 3136.0);
    vr = dS[256 + t] * (1.0 / 3136.0) - s * s;
    scale = gds[t] * rsqrtf((float)vr + 1e-5f);
    sdc[t] = scale; sdb[t] = bds[t] - (float)s * scale;
  }
  __syncthreads();
  #pragma unroll
  for (int k = 0; k < 4; k++){
    int n = blockIdx.x * 1024 + k * 256 + t;
    int c = (n / HW) & 255;
    float h = out[n], aa = A[n];
    float r = fmaxf(aa * sdc[c] + sdb[c], 0.0f);
    out[n] = fmaxf(h * s3c[c] + s3b[c] + r, 0.0f);
  }
  if (blockIdx.x == 0 && t == 0){
    const int ns[4] = {32768, 8192, 36864, 16384};
    float kl = 0.0f;
    #pragma unroll
    for (int q = 0; q < 4; q++){
      double se  = dS[1280 + q * 4];
      double sel = dS[1280 + q * 4 + 1];
      double sef = dS[1280 + q * 4 + 2];
      double sq  = dS[1280 + q * 4 + 3];
      kl += (float)((((sel - sef) / se) - log(se) + log(sq)) / (double)ns[q]);
    }
    out[802816] = kl;
  }
}

// ===========================================================================
extern "C" void kernel_launch(void* const* d_in, const int* in_sizes, int n_in,
                              void* d_out, int out_size, void* d_ws, size_t ws_size,
                              hipStream_t stream)
{
  const float* x      = (const float*)d_in[0];
  const float* sw_ds  = (const float*)d_in[1];
  const float* sw_c1  = (const float*)d_in[2];
  const float* sw_c2  = (const float*)d_in[3];
  const float* sw_c3  = (const float*)d_in[4];
  const float* a_ds   = (const float*)d_in[5];
  const float* a_c1   = (const float*)d_in[6];
  const float* a_c2   = (const float*)d_in[7];
  const float* a_c3   = (const float*)d_in[8];
  const float* peg_w  = (const float*)d_in[9];
  const float* bn1_g  = (const float*)d_in[10];
  const float* bn1_b  = (const float*)d_in[11];
  const float* bn2_g  = (const float*)d_in[12];
  const float* bn2_b  = (const float*)d_in[13];
  const float* bn3_g  = (const float*)d_in[14];
  const float* bn3_b  = (const float*)d_in[15];
  const float* bnds_g = (const float*)d_in[16];
  const float* bnds_b = (const float*)d_in[17];
  const float* lap_ds = (const float*)d_in[18];
  const float* lap_c1 = (const float*)d_in[19];
  const float* lap_c2 = (const float*)d_in[20];
  const float* lap_c3 = (const float*)d_in[21];

  float* ws    = (float*)d_ws;
  float* f_c2  = ws;                        // 36864
  float* mmbuf = ws + 36864;                // 128
  double* dstat= (double*)(ws + 37120);     // 1344 doubles -> 2688 floats
  float* A     = ws + 39808;                // 802816
  float* T3    = ws + 842624;               // 200704
  float* T2b   = ws + 1043328;              // 245760 (padded raw c1+PEG out)

  float* out = (float*)d_out;

  minmax_kernel<<<64, 256, 0, stream>>>(
      sw_ds, 32768, sw_c1, 8192, sw_c2, 36864, sw_c3, 16384, mmbuf, dstat);

  front_kernel<<<848, 256, 0, stream>>>(
      x, sw_ds, a_ds, lap_ds, sw_c1, a_c1, lap_c1,
      sw_c2, a_c2, lap_c2, f_c2, sw_c3, a_c3, lap_c3,
      peg_w, mmbuf, A, T2b, dstat);

  mid3x3_kernel<<<512, 256, 0, stream>>>(T2b, f_c2, bn1_g, bn1_b, T3, dstat);

  back_kernel<<<1024, 256, 0, stream>>>(T3, sw_c3, a_c3, mmbuf,
                                        bn2_g, bn2_b, out, dstat);

  final_kernel<<<784, 256, 0, stream>>>(out, A, bn3_g, bn3_b, bnds_g, bnds_b,
                                        dstat);
}